// Round 6
// baseline (275.513 us; speedup 1.0000x reference)
//
#include <hip/hip_runtime.h>
#include <math.h>

// Shapes (fixed)
#define B_ 4
#define S_ 256
#define N_ 32
#define H_ 256
#define NH_ 8
#define HD_ 32
#define FF_ 512
#define BN_ 128
#define M_ 32768   // BN_*S_
#define BS_ 1024   // B_*S_

typedef __attribute__((ext_vector_type(8))) short short8;
typedef __attribute__((ext_vector_type(4))) short short4v;
typedef __attribute__((ext_vector_type(4))) float f32x4;
typedef __attribute__((ext_vector_type(16))) float f32x16;
typedef __attribute__((ext_vector_type(2))) unsigned long long u64x2;

__device__ __forceinline__ unsigned short f2bf(float f) {
  unsigned u = __builtin_bit_cast(unsigned, f);
  u = (u + 0x7FFFu + ((u >> 16) & 1u)) >> 16;
  return (unsigned short)u;
}
__device__ __forceinline__ float bf2f(unsigned short h) {
  unsigned u = ((unsigned)h) << 16;
  return __builtin_bit_cast(float, u);
}

// ---------------------------------------------------------------------------
// time_state[bs, h] (fp32)
// ---------------------------------------------------------------------------
__global__ __launch_bounds__(256)
void ts_kernel(const float* __restrict__ reg, const float* __restrict__ tr,
               const int* __restrict__ codes,
               const float* __restrict__ sess_emb,
               const float* __restrict__ reg_w, const float* __restrict__ reg_b,
               const float* __restrict__ tr_w, const float* __restrict__ tr_b,
               float* __restrict__ ts) {
  const int bs = blockIdx.x;
  const int h = threadIdx.x;
  int c = codes[bs];
  c = c < 0 ? 0 : (c > 7 ? 7 : c);
  const float r = reg[bs], t = tr[bs];
  ts[bs * H_ + h] = sess_emb[c * H_ + h] + r * reg_w[h] + reg_b[h]
                    + t * tr_w[h] + tr_b[h];
}

// ---------------------------------------------------------------------------
// All weight conversions in one launch. W[K][N] fp32 -> Wt[N][K] bf16.
// Region table by blockIdx.x (2560 blocks x 256 thr).
// ---------------------------------------------------------------------------
__global__ __launch_bounds__(256)
void cvtall_kernel(const float* __restrict__ q_w, const float* __restrict__ k_w,
                   const float* __restrict__ v_w, const float* __restrict__ o_w,
                   const float* __restrict__ tq_w, const float* __restrict__ tk_w,
                   const float* __restrict__ ff1_w, const float* __restrict__ ff2_w,
                   unsigned short* __restrict__ wqk, unsigned short* __restrict__ wv,
                   unsigned short* __restrict__ wo, unsigned short* __restrict__ wtqtk,
                   unsigned short* __restrict__ wff1, unsigned short* __restrict__ wff2) {
  const int bid = blockIdx.x, tid = threadIdx.x;
  const float* src; unsigned short* dst; int ns, K, base;
  if (bid < 256)       { src = q_w;   dst = wqk;           ns = 8; K = 256; base = 0; }
  else if (bid < 512)  { src = k_w;   dst = wqk + 65536;   ns = 8; K = 256; base = 256; }
  else if (bid < 768)  { src = v_w;   dst = wv;            ns = 8; K = 256; base = 512; }
  else if (bid < 1024) { src = o_w;   dst = wo;            ns = 8; K = 256; base = 768; }
  else if (bid < 1280) { src = tq_w;  dst = wtqtk;         ns = 8; K = 256; base = 1024; }
  else if (bid < 1536) { src = tk_w;  dst = wtqtk + 65536; ns = 8; K = 256; base = 1280; }
  else if (bid < 2048) { src = ff1_w; dst = wff1;          ns = 9; K = 256; base = 1536; }
  else                 { src = ff2_w; dst = wff2;          ns = 8; K = 512; base = 2048; }
  const int idx = (bid - base) * 256 + tid;
  const int k = idx >> ns, n = idx & ((1 << ns) - 1);
  dst[n * K + k] = f2bf(src[idx]);
}

// ---------------------------------------------------------------------------
// Prep: flatb = bf16(seq gathered to [M,256]); fpb = bf16(seq + ts).
// ---------------------------------------------------------------------------
__global__ __launch_bounds__(256)
void prep_kernel(const float* __restrict__ seq, const float* __restrict__ ts,
                 unsigned short* __restrict__ flatb, unsigned short* __restrict__ fpb) {
  const int row = blockIdx.x * 8 + (threadIdx.x >> 5);
  const int c0 = (threadIdx.x & 31) * 8;
  const int bn = row >> 8, s = row & 255;
  const int b = bn >> 5, n = bn & 31;
  const float* sp = &seq[((((b << 8) + s) << 5) + n) * 256 + c0];
  const float* tp = &ts[(((b << 8) + s) << 8) + c0];
  const float4 a0 = *(const float4*)sp, a1 = *(const float4*)(sp + 4);
  const float4 t0 = *(const float4*)tp, t1 = *(const float4*)(tp + 4);
  short8 fv, gv;
  fv[0] = (short)f2bf(a0.x); fv[1] = (short)f2bf(a0.y);
  fv[2] = (short)f2bf(a0.z); fv[3] = (short)f2bf(a0.w);
  fv[4] = (short)f2bf(a1.x); fv[5] = (short)f2bf(a1.y);
  fv[6] = (short)f2bf(a1.z); fv[7] = (short)f2bf(a1.w);
  gv[0] = (short)f2bf(a0.x + t0.x); gv[1] = (short)f2bf(a0.y + t0.y);
  gv[2] = (short)f2bf(a0.z + t0.z); gv[3] = (short)f2bf(a0.w + t0.w);
  gv[4] = (short)f2bf(a1.x + t1.x); gv[5] = (short)f2bf(a1.y + t1.y);
  gv[6] = (short)f2bf(a1.z + t1.z); gv[7] = (short)f2bf(a1.w + t1.w);
  *(short8*)&flatb[row * 256 + c0] = fv;
  *(short8*)&fpb[row * 256 + c0] = gv;
}

// ---------------------------------------------------------------------------
// bf16 MFMA GEMM: C[M,NOUT] = epilogue(A @ W + bias)
// AMODE: 0 = fp32 A[M,K]; 3 = bf16 A[M,K]
// RESMODE: 0 none; 2 + resb (bf16 [M,NOUT])
// DUALB: bias for col<256, bias2 for col>=256. SCALEH: post_scale only col<256.
// OUTBF: write bf16 (else fp32). 128x128 tile, BK=64, 256 thr (4 waves 2x2).
// ---------------------------------------------------------------------------
template<int AMODE, int RESMODE, bool GELU_, int K, int NOUT, bool OUTBF,
         bool DUALB, bool SCALEH>
__global__ __launch_bounds__(256)
void mmb_kernel(const void* __restrict__ Av, const unsigned short* __restrict__ Wt,
                const float* __restrict__ bias, const float* __restrict__ bias2,
                const unsigned short* __restrict__ resb,
                void* __restrict__ Cv, float post_scale) {
  __shared__ unsigned short As[128][72];
  __shared__ unsigned short Bs[128][72];
  const int tid = threadIdx.x;
  const int m0 = blockIdx.x * 128, n0 = blockIdx.y * 128;
  const int l = tid & 63, w = tid >> 6;
  const int wr = w >> 1, wc = w & 1;
  const int lr = l & 15, lg = l >> 4;
  f32x4 acc[4][4] = {};

  for (int k0 = 0; k0 < K; k0 += 64) {
    if (AMODE == 3) {
      const unsigned short* Ab = (const unsigned short*)Av;
#pragma unroll
      for (int i = 0; i < 4; ++i) {
        const int seg = i * 256 + tid;
        const int r = seg >> 3, c8 = (seg & 7) * 8;
        const short8 v = *(const short8*)&Ab[(m0 + r) * K + k0 + c8];
        *(short8*)&As[r][c8] = v;
      }
    } else {
#pragma unroll
      for (int i = 0; i < 8; ++i) {
        const int seg = i * 256 + tid;
        const int r = seg >> 4, c4 = (seg & 15) * 4;
        const float4 a4 = *(const float4*)&((const float*)Av)[(m0 + r) * K + k0 + c4];
        short4v sv;
        sv[0] = (short)f2bf(a4.x); sv[1] = (short)f2bf(a4.y);
        sv[2] = (short)f2bf(a4.z); sv[3] = (short)f2bf(a4.w);
        *(short4v*)&As[r][c4] = sv;
      }
    }
#pragma unroll
    for (int i = 0; i < 4; ++i) {
      const int seg = i * 256 + tid;
      const int n = seg >> 3, c8 = (seg & 7) * 8;
      const short8 v = *(const short8*)&Wt[(n0 + n) * K + k0 + c8];
      *(short8*)&Bs[n][c8] = v;
    }
    __syncthreads();
#pragma unroll
    for (int ks = 0; ks < 2; ++ks) {
      short8 af[4], bfr[4];
#pragma unroll
      for (int qt = 0; qt < 4; ++qt)
        af[qt] = *(const short8*)&As[wr * 64 + qt * 16 + lr][ks * 32 + lg * 8];
#pragma unroll
      for (int nt = 0; nt < 4; ++nt)
        bfr[nt] = *(const short8*)&Bs[wc * 64 + nt * 16 + lr][ks * 32 + lg * 8];
#pragma unroll
      for (int qt = 0; qt < 4; ++qt)
#pragma unroll
        for (int nt = 0; nt < 4; ++nt)
          acc[qt][nt] = __builtin_amdgcn_mfma_f32_16x16x32_bf16(
              af[qt], bfr[nt], acc[qt][nt], 0, 0, 0);
    }
    __syncthreads();
  }

#pragma unroll
  for (int qt = 0; qt < 4; ++qt) {
#pragma unroll
    for (int nt = 0; nt < 4; ++nt) {
      const int col = n0 + wc * 64 + nt * 16 + lr;
      const float bsv = DUALB ? (col < 256 ? bias[col] : bias2[col - 256])
                              : bias[col];
      const float sc = SCALEH ? (col < 256 ? post_scale : 1.0f) : post_scale;
#pragma unroll
      for (int i = 0; i < 4; ++i) {
        const int row = m0 + wr * 64 + qt * 16 + (lg << 2) + i;
        float v = (acc[qt][nt][i] + bsv) * sc;
        if (RESMODE == 2) v += bf2f(resb[row * NOUT + col]);
        if (GELU_) v = 0.5f * v * (1.0f + erff(v * 0.70710678118654752f));
        if (OUTBF) ((unsigned short*)Cv)[row * NOUT + col] = f2bf(v);
        else       ((float*)Cv)[row * NOUT + col] = v;
      }
    }
  }
}

// ---------------------------------------------------------------------------
// Attention v4: balanced swapped-operand 32x32 MFMA flash.
// 4 waves x 256 thr; wave w owns query chunks {w, 7-w} (2 online states per
// lane) -> every wave does exactly 9 key-group-sets (no triangular tail).
// K-fragment LDS reads shared between the two query sets.
// P redistribution via per-wave LDS bounce (semantics-free, v3-proven).
// ---------------------------------------------------------------------------
__device__ __forceinline__ void softmax_pv(
    f32x16& sacc, f32x16& oacc, float& mrun, float& lrun,
    const int qa, const int kbase, const int hi, const int lq,
    const unsigned wnd, char* __restrict__ Pw, const char* __restrict__ VsB) {
  const float c2 = 0.25505402f;  // (1/sqrt(32)) * log2(e)
#pragma unroll
  for (int r = 0; r < 16; ++r) {
    const int crow = (r & 3) + 8 * (r >> 2) + 4 * hi;
    const int key = kbase + crow;
    const bool ok = (key <= qa) && (((wnd >> crow) & 1u) != 0u);
    sacc[r] = ok ? sacc[r] * c2 : -1e30f;
  }
  float g0 = fmaxf(fmaxf(sacc[0], sacc[1]), fmaxf(sacc[2], sacc[3]));
  float g1 = fmaxf(fmaxf(sacc[4], sacc[5]), fmaxf(sacc[6], sacc[7]));
  float g2 = fmaxf(fmaxf(sacc[8], sacc[9]), fmaxf(sacc[10], sacc[11]));
  float g3 = fmaxf(fmaxf(sacc[12], sacc[13]), fmaxf(sacc[14], sacc[15]));
  float gmax = fmaxf(fmaxf(g0, g1), fmaxf(g2, g3));
  gmax = fmaxf(gmax, __shfl_xor(gmax, 32));
  const float mnew = fmaxf(mrun, gmax);
  const float f = __builtin_amdgcn_exp2f(mrun - mnew);
  mrun = mnew;
  lrun *= f;
#pragma unroll
  for (int r = 0; r < 16; ++r) oacc[r] *= f;
#pragma unroll
  for (int r = 0; r < 16; ++r) {
    const float p = __builtin_amdgcn_exp2f(sacc[r] - mnew);
    sacc[r] = (sacc[r] < -1e29f) ? 0.0f : p;
  }
  float rs = ((sacc[0] + sacc[1]) + (sacc[2] + sacc[3]))
           + ((sacc[4] + sacc[5]) + (sacc[6] + sacc[7]))
           + ((sacc[8] + sacc[9]) + (sacc[10] + sacc[11]))
           + ((sacc[12] + sacc[13]) + (sacc[14] + sacc[15]));
  rs += __shfl_xor(rs, 32);
  lrun += rs;
  // P bounce: write P[key32][q32] per HW-verified C/D mapping, read B-frag.
#pragma unroll
  for (int r = 0; r < 16; ++r) {
    const int crow = (r & 3) + 8 * (r >> 2) + 4 * hi;
    *(unsigned short*)(Pw + crow * 64 + lq * 2) = f2bf(sacc[r]);
  }
  asm volatile("" ::: "memory");
  short8 pf0, pf1;
#pragma unroll
  for (int j = 0; j < 8; ++j) {
    pf0[j] = (short)*(const unsigned short*)(Pw + (hi * 8 + j) * 64 + lq * 2);
    pf1[j] = (short)*(const unsigned short*)(Pw + (16 + hi * 8 + j) * 64 + lq * 2);
  }
  {
    const short8 avf = *(const short8*)(
        VsB + lq * 512 + (((kbase + hi * 8) * 2) ^ ((lq & 7) << 4)));
    oacc = __builtin_amdgcn_mfma_f32_32x32x16_bf16(avf, pf0, oacc, 0, 0, 0);
  }
  {
    const short8 avf = *(const short8*)(
        VsB + lq * 512 + (((kbase + 16 + hi * 8) * 2) ^ ((lq & 7) << 4)));
    oacc = __builtin_amdgcn_mfma_f32_32x32x16_bf16(avf, pf1, oacc, 0, 0, 0);
  }
}

__global__ __launch_bounds__(256, 2)
void attn3_kernel(const unsigned short* __restrict__ qkb,   // [M][512] q|k
                  const unsigned short* __restrict__ vb,    // [M][256]
                  const unsigned short* __restrict__ tqtkb, // [BS][512] tq|tk
                  const int* __restrict__ valid,
                  unsigned short* __restrict__ ao) {
  __shared__ __align__(16) char KsB[256 * 128];   // K' [key][d64], swizzled
  __shared__ __align__(16) char VsB[32 * 512];    // V^T [dv][key], swizzled
  __shared__ __align__(16) char PwB[4 * 2048];    // per-wave P/O bounce

  const int bh = blockIdx.x;
  const int bn = bh >> 3, h = bh & 7;
  const int b = bn >> 5, n = bn & 31;
  const int tid = threadIdx.x, l = tid & 63, w = tid >> 6;   // w in 0..3
  const int lq = l & 31, hi = l >> 5;
  const int qa0 = w * 32 + lq;          // low chunk query
  const int qa1 = (7 - w) * 32 + lq;    // high chunk query

  const unsigned long long bm0 = __ballot(valid[((b << 8) + 0   + l) * 32 + n] != 0);
  const unsigned long long bm1 = __ballot(valid[((b << 8) + 64  + l) * 32 + n] != 0);
  const unsigned long long bm2 = __ballot(valid[((b << 8) + 128 + l) * 32 + n] != 0);
  const unsigned long long bm3 = __ballot(valid[((b << 8) + 192 + l) * 32 + n] != 0);

  // Q' fragments for both sets (B-operand): k = 8*hi + j per 16-wide chunk
  short8 qf0[4], qf1[4];
  {
    const unsigned short* qp = &qkb[((bn << 8) + qa0) * 512 + (h << 5)];
    const unsigned short* tp = &tqtkb[((b << 8) + qa0) * 512 + (h << 5)];
    qf0[0] = *(const short8*)&qp[hi * 8];
    qf0[1] = *(const short8*)&qp[16 + hi * 8];
    qf0[2] = *(const short8*)&tp[hi * 8];
    qf0[3] = *(const short8*)&tp[16 + hi * 8];
  }
  {
    const unsigned short* qp = &qkb[((bn << 8) + qa1) * 512 + (h << 5)];
    const unsigned short* tp = &tqtkb[((b << 8) + qa1) * 512 + (h << 5)];
    qf1[0] = *(const short8*)&qp[hi * 8];
    qf1[1] = *(const short8*)&qp[16 + hi * 8];
    qf1[2] = *(const short8*)&tp[hi * 8];
    qf1[3] = *(const short8*)&tp[16 + hi * 8];
  }

  // stage K' (k | tk), swizzled: byte = key*128 + ((c*16) ^ ((key&7)<<4))
#pragma unroll
  for (int i = 0; i < 8; ++i) {
    const int e = i * 256 + tid;
    const int key = e >> 3, c = e & 7;
    const unsigned short* src = (c < 4)
        ? &qkb[((bn << 8) + key) * 512 + 256 + (h << 5) + c * 8]
        : &tqtkb[((b << 8) + key) * 512 + 256 + (h << 5) + (c - 4) * 8];
    *(short8*)(KsB + key * 128 + ((c * 16) ^ ((key & 7) << 4))) = *(const short8*)src;
  }
  // stage V^T, swizzled: byte = dv*512 + ((key*2) ^ ((dv&7)<<4))
#pragma unroll
  for (int i = 0; i < 4; ++i) {
    const int e = i * 256 + tid;
    const int key = e >> 2, c = e & 3;
    const short8 v = *(const short8*)&vb[((bn << 8) + key) * 256 + (h << 5) + c * 8];
#pragma unroll
    for (int j = 0; j < 8; ++j) {
      const int dv = c * 8 + j;
      *(unsigned short*)(VsB + dv * 512 + ((key * 2) ^ ((dv & 7) << 4))) =
          (unsigned short)v[j];
    }
  }
  __syncthreads();

  char* Pw = PwB + w * 2048;
  f32x16 oacc0 = {}, oacc1 = {};
  float m0r = -1e30f, l0r = 0.0f, m1r = -1e30f, l1r = 0.0f;

  const int gN = 7 - w;
  for (int g = 0; g <= gN; ++g) {
    const int kbase = g << 5;
    short8 akf[4];
#pragma unroll
    for (int df = 0; df < 4; ++df) {
      const int key = kbase + lq;
      akf[df] = *(const short8*)(
          KsB + key * 128 + ((df * 32 + hi * 16) ^ ((key & 7) << 4)));
    }
    const unsigned long long bmc = (kbase < 64) ? bm0 : (kbase < 128) ? bm1
                                 : (kbase < 192) ? bm2 : bm3;
    const unsigned wnd = (kbase & 32) ? (unsigned)(bmc >> 32) : (unsigned)bmc;
    if (g <= w) {
      f32x16 s = {};
#pragma unroll
      for (int df = 0; df < 4; ++df)
        s = __builtin_amdgcn_mfma_f32_32x32x16_bf16(akf[df], qf0[df], s, 0, 0, 0);
      softmax_pv(s, oacc0, m0r, l0r, qa0, kbase, hi, lq, wnd, Pw, VsB);
    }
    {
      f32x16 s = {};
#pragma unroll
      for (int df = 0; df < 4; ++df)
        s = __builtin_amdgcn_mfma_f32_32x32x16_bf16(akf[df], qf1[df], s, 0, 0, 0);
      softmax_pv(s, oacc1, m1r, l1r, qa1, kbase, hi, lq, wnd, Pw, VsB);
    }
  }

  // degenerate rows: no valid causal key -> uniform over ALL valid keys
#pragma unroll
  for (int set = 0; set < 2; ++set) {
    float& lr_ = set ? l1r : l0r;
    f32x16& oa = set ? oacc1 : oacc0;
    if (lr_ == 0.0f) {
      float cnt = 0.0f;
      f32x16 os = {};
      for (int key = 0; key < 256; ++key) {
        const unsigned long long bmc = (key < 64) ? bm0 : (key < 128) ? bm1
                                     : (key < 192) ? bm2 : bm3;
        if ((bmc >> (key & 63)) & 1ull) {
          cnt += 1.0f;
#pragma unroll
          for (int r = 0; r < 16; ++r) {
            const int dv = (r & 3) + 8 * (r >> 2) + 4 * hi;
            os[r] += bf2f(*(const unsigned short*)(
                VsB + dv * 512 + ((key * 2) ^ ((dv & 7) << 4))));
          }
        }
      }
      oa = os; lr_ = cnt;
    }
  }

  // store both sets (transpose via per-wave LDS bounce, swizzled rows)
#pragma unroll
  for (int set = 0; set < 2; ++set) {
    const float lr_ = set ? l1r : l0r;
    const f32x16& oa = set ? oacc1 : oacc0;
    const int qbase = (set ? (7 - w) : w) * 32;
    const float inv = 1.0f / fmaxf(lr_, 1e-6f);
    asm volatile("s_waitcnt lgkmcnt(0)" ::: "memory");  // WAR vs prior bounce
#pragma unroll
    for (int r = 0; r < 16; ++r) {
      const int dv = (r & 3) + 8 * (r >> 2) + 4 * hi;
      *(unsigned short*)(Pw + lq * 64 + ((dv * 2) ^ ((lq & 7) << 3))) =
          f2bf(oa[r] * inv);
    }
    asm volatile("s_waitcnt lgkmcnt(0)" ::: "memory");
    {
      const int q2 = l >> 1, h2 = l & 1;
      unsigned long long d0, d1, d2, d3;
      d0 = *(const unsigned long long*)(Pw + q2 * 64 + (((h2 * 4 + 0) ^ (q2 & 7)) << 3));
      d1 = *(const unsigned long long*)(Pw + q2 * 64 + (((h2 * 4 + 1) ^ (q2 & 7)) << 3));
      d2 = *(const unsigned long long*)(Pw + q2 * 64 + (((h2 * 4 + 2) ^ (q2 & 7)) << 3));
      d3 = *(const unsigned long long*)(Pw + q2 * 64 + (((h2 * 4 + 3) ^ (q2 & 7)) << 3));
      u64x2 sv0, sv1;
      sv0[0] = d0; sv0[1] = d1; sv1[0] = d2; sv1[1] = d3;
      unsigned short* op = &ao[(((bn << 8) + qbase + q2) << 8) + (h << 5) + h2 * 16];
      *(u64x2*)op = sv0;
      *(u64x2*)(op + 8) = sv1;
    }
  }
}

// ---------------------------------------------------------------------------
// LN1: fp32 in -> bf16 out (flat). LN2: fp32 in -> fp32 out, *valid, scatter.
// ---------------------------------------------------------------------------
__global__ __launch_bounds__(256)
void ln1_kernel(const float* __restrict__ X, const float* __restrict__ g,
                const float* __restrict__ bb, unsigned short* __restrict__ out) {
  const int row = blockIdx.x * 4 + (threadIdx.x >> 6);
  const int lane = threadIdx.x & 63;
  const float4 x = *(const float4*)&X[row * 256 + lane * 4];
  float s1 = x.x + x.y + x.z + x.w;
#pragma unroll
  for (int off = 1; off < 64; off <<= 1) s1 += __shfl_xor(s1, off);
  const float mean = s1 * (1.0f / 256.0f);
  const float dx = x.x - mean, dy = x.y - mean, dz = x.z - mean, dw = x.w - mean;
  float s2 = dx * dx + dy * dy + dz * dz + dw * dw;
#pragma unroll
  for (int off = 1; off < 64; off <<= 1) s2 += __shfl_xor(s2, off);
  const float rstd = rsqrtf(s2 * (1.0f / 256.0f) + 1e-5f);
  const int c0 = lane * 4;
  short4v y;
  y[0] = (short)f2bf(dx * rstd * g[c0] + bb[c0]);
  y[1] = (short)f2bf(dy * rstd * g[c0 + 1] + bb[c0 + 1]);
  y[2] = (short)f2bf(dz * rstd * g[c0 + 2] + bb[c0 + 2]);
  y[3] = (short)f2bf(dw * rstd * g[c0 + 3] + bb[c0 + 3]);
  *(short4v*)&out[row * 256 + c0] = y;
}

__global__ __launch_bounds__(256)
void ln2_kernel(const float* __restrict__ X, const float* __restrict__ g,
                const float* __restrict__ bb, float* __restrict__ out,
                const int* __restrict__ valid) {
  const int row = blockIdx.x * 4 + (threadIdx.x >> 6);
  const int lane = threadIdx.x & 63;
  const float4 x = *(const float4*)&X[row * 256 + lane * 4];
  float s1 = x.x + x.y + x.z + x.w;
#pragma unroll
  for (int off = 1; off < 64; off <<= 1) s1 += __shfl_xor(s1, off);
  const float mean = s1 * (1.0f / 256.0f);
  const float dx = x.x - mean, dy = x.y - mean, dz = x.z - mean, dw = x.w - mean;
  float s2 = dx * dx + dy * dy + dz * dz + dw * dw;
#pragma unroll
  for (int off = 1; off < 64; off <<= 1) s2 += __shfl_xor(s2, off);
  const float rstd = rsqrtf(s2 * (1.0f / 256.0f) + 1e-5f);
  const int c0 = lane * 4;
  const int bn = row >> 8, s = row & 255;
  const int b = bn >> 5, n = bn & 31;
  const float vmv = (valid[((b << 8) + s) * 32 + n] != 0) ? 1.0f : 0.0f;
  float4 y;
  y.x = (dx * rstd * g[c0] + bb[c0]) * vmv;
  y.y = (dy * rstd * g[c0 + 1] + bb[c0 + 1]) * vmv;
  y.z = (dz * rstd * g[c0 + 2] + bb[c0 + 2]) * vmv;
  y.w = (dw * rstd * g[c0 + 3] + bb[c0 + 3]) * vmv;
  *(float4*)&out[(((((b << 8) + s) << 5) + n) << 8) + c0] = y;
}

// ---------------------------------------------------------------------------
extern "C" void kernel_launch(void* const* d_in, const int* in_sizes, int n_in,
                              void* d_out, int out_size, void* d_ws, size_t ws_size,
                              hipStream_t stream) {
  const float* seq    = (const float*)d_in[0];
  const float* regs   = (const float*)d_in[1];
  const float* trs    = (const float*)d_in[2];
  const float* q_w    = (const float*)d_in[3];
  const float* q_b    = (const float*)d_in[4];
  const float* k_w    = (const float*)d_in[5];
  const float* k_b    = (const float*)d_in[6];
  const float* v_w    = (const float*)d_in[7];
  const float* v_b    = (const float*)d_in[8];
  const float* o_w    = (const float*)d_in[9];
  const float* o_b    = (const float*)d_in[10];
  const float* semb   = (const float*)d_in[11];
  const float* reg_w  = (const float*)d_in[12];
  const float* reg_b  = (const float*)d_in[13];
  const float* tr_w   = (const float*)d_in[14];
  const float* tr_b   = (const float*)d_in[15];
  const float* tq_w   = (const float*)d_in[16];
  const float* tq_b   = (const float*)d_in[17];
  const float* tk_w   = (const float*)d_in[18];
  const float* tk_b   = (const float*)d_in[19];
  const float* ff_w1  = (const float*)d_in[20];
  const float* ff_b1  = (const float*)d_in[21];
  const float* ff_w2  = (const float*)d_in[22];
  const float* ff_b2  = (const float*)d_in[23];
  const float* ln1_g  = (const float*)d_in[24];
  const float* ln1_b  = (const float*)d_in[25];
  const float* ln2_g  = (const float*)d_in[26];
  const float* ln2_b  = (const float*)d_in[27];
  const int*   valid  = (const int*)d_in[28];
  const int*   codes  = (const int*)d_in[29];

  float* f32ws = (float*)d_ws;
  float* ts    = f32ws;                 // 262144 f
  float* x1pre = f32ws + 262144;        // 8388608 f (reused as x2)
  unsigned short* bws = (unsigned short*)(f32ws + 262144 + 8388608);
  unsigned short* flatb = bws;                    // 8388608  (x1b alias)
  unsigned short* fpb   = bws + 8388608;          // 8388608  (ao alias)
  unsigned short* qkb   = bws + 16777216;         // 16777216 (h1 alias)
  unsigned short* vb    = bws + 33554432;         // 8388608
  unsigned short* tqtkb = bws + 41943040;         // 524288
  unsigned short* wqk   = bws + 42467328;         // 131072
  unsigned short* wv    = bws + 42598400;         // 65536
  unsigned short* wo    = bws + 42663936;         // 65536
  unsigned short* wtqtk = bws + 42729472;         // 131072
  unsigned short* wff1  = bws + 42860544;         // 131072
  unsigned short* wff2  = bws + 42991616;         // 131072  (end 43122688)
  unsigned short* ao  = fpb;
  unsigned short* x1b = flatb;
  unsigned short* h1  = qkb;
  float* x2 = x1pre;
  float* outp = (float*)d_out;

  // 1. time state + weight conversion (independent)
  ts_kernel<<<BS_, 256, 0, stream>>>(regs, trs, codes, semb, reg_w, reg_b,
                                     tr_w, tr_b, ts);
  cvtall_kernel<<<2560, 256, 0, stream>>>(q_w, k_w, v_w, o_w, tq_w, tk_w,
                                          ff_w1, ff_w2, wqk, wv, wo, wtqtk,
                                          wff1, wff2);
  // 2. prep: flatb = bf16(flat), fpb = bf16(flat + ts)
  prep_kernel<<<M_ / 8, 256, 0, stream>>>(seq, ts, flatb, fpb);
  // 3. temporal projections merged (tq|tk), 0.25 folded into tq half
  mmb_kernel<0, 0, false, 256, 512, true, true, true>
      <<<dim3(8, 4), 256, 0, stream>>>(ts, wtqtk, tq_b, tk_b, nullptr,
                                       tqtkb, 0.25f);
  // 4. q|k merged projection; v projection
  mmb_kernel<3, 0, false, 256, 512, true, true, false>
      <<<dim3(256, 4), 256, 0, stream>>>(fpb, wqk, q_b, k_b, nullptr,
                                         qkb, 1.0f);
  mmb_kernel<3, 0, false, 256, 256, true, false, false>
      <<<dim3(256, 2), 256, 0, stream>>>(flatb, wv, v_b, nullptr, nullptr,
                                         vb, 1.0f);
  // 5. attention (v4: balanced waves)
  attn3_kernel<<<BN_ * NH_, 256, 0, stream>>>(qkb, vb, tqtkb, valid, ao);
  // 6. o-proj + flat residual (bf16) -> x1pre (fp32); LN1 -> x1b (bf16)
  mmb_kernel<3, 2, false, 256, 256, false, false, false>
      <<<dim3(256, 2), 256, 0, stream>>>(ao, wo, o_b, nullptr, flatb,
                                         x1pre, 1.0f);
  ln1_kernel<<<M_ / 4, 256, 0, stream>>>(x1pre, ln1_g, ln1_b, x1b);
  // 7. FF
  mmb_kernel<3, 0, true, 256, 512, true, false, false>
      <<<dim3(256, 4), 256, 0, stream>>>(x1b, wff1, ff_b1, nullptr, nullptr,
                                         h1, 1.0f);
  mmb_kernel<3, 2, false, 512, 256, false, false, false>
      <<<dim3(256, 2), 256, 0, stream>>>(h1, wff2, ff_b2, nullptr, x1b,
                                         x2, 1.0f);
  // 8. LN2 * valid -> output layout
  ln2_kernel<<<M_ / 4, 256, 0, stream>>>(x2, ln2_g, ln2_b, outp, valid);
}

// Round 7
// 246.948 us; speedup vs baseline: 1.1157x; 1.1157x over previous
//
#include <hip/hip_runtime.h>
#include <math.h>

// Shapes (fixed)
#define B_ 4
#define S_ 256
#define N_ 32
#define H_ 256
#define NH_ 8
#define HD_ 32
#define FF_ 512
#define BN_ 128
#define M_ 32768   // BN_*S_
#define BS_ 1024   // B_*S_

typedef __attribute__((ext_vector_type(8))) short short8;
typedef __attribute__((ext_vector_type(4))) short short4v;
typedef __attribute__((ext_vector_type(4))) float f32x4;
typedef __attribute__((ext_vector_type(16))) float f32x16;
typedef __attribute__((ext_vector_type(4))) int i32x4;

__device__ __forceinline__ unsigned short f2bf(float f) {
  unsigned u = __builtin_bit_cast(unsigned, f);
  u = (u + 0x7FFFu + ((u >> 16) & 1u)) >> 16;
  return (unsigned short)u;
}
__device__ __forceinline__ float bf2f(unsigned short h) {
  unsigned u = ((unsigned)h) << 16;
  return __builtin_bit_cast(float, u);
}

// ---------------------------------------------------------------------------
// time_state[bs, h] (fp32)
// ---------------------------------------------------------------------------
__global__ __launch_bounds__(256)
void ts_kernel(const float* __restrict__ reg, const float* __restrict__ tr,
               const int* __restrict__ codes,
               const float* __restrict__ sess_emb,
               const float* __restrict__ reg_w, const float* __restrict__ reg_b,
               const float* __restrict__ tr_w, const float* __restrict__ tr_b,
               float* __restrict__ ts) {
  const int bs = blockIdx.x;
  const int h = threadIdx.x;
  int c = codes[bs];
  c = c < 0 ? 0 : (c > 7 ? 7 : c);
  const float r = reg[bs], t = tr[bs];
  ts[bs * H_ + h] = sess_emb[c * H_ + h] + r * reg_w[h] + reg_b[h]
                    + t * tr_w[h] + tr_b[h];
}

// ---------------------------------------------------------------------------
// All weight conversions in one launch. W[K][N] fp32 -> Wt[N][K] bf16.
// ---------------------------------------------------------------------------
__global__ __launch_bounds__(256)
void cvtall_kernel(const float* __restrict__ q_w, const float* __restrict__ k_w,
                   const float* __restrict__ v_w, const float* __restrict__ o_w,
                   const float* __restrict__ tq_w, const float* __restrict__ tk_w,
                   const float* __restrict__ ff1_w, const float* __restrict__ ff2_w,
                   unsigned short* __restrict__ wqk, unsigned short* __restrict__ wv,
                   unsigned short* __restrict__ wo, unsigned short* __restrict__ wtqtk,
                   unsigned short* __restrict__ wff1, unsigned short* __restrict__ wff2) {
  const int bid = blockIdx.x, tid = threadIdx.x;
  const float* src; unsigned short* dst; int ns, K, base;
  if (bid < 256)       { src = q_w;   dst = wqk;           ns = 8; K = 256; base = 0; }
  else if (bid < 512)  { src = k_w;   dst = wqk + 65536;   ns = 8; K = 256; base = 256; }
  else if (bid < 768)  { src = v_w;   dst = wv;            ns = 8; K = 256; base = 512; }
  else if (bid < 1024) { src = o_w;   dst = wo;            ns = 8; K = 256; base = 768; }
  else if (bid < 1280) { src = tq_w;  dst = wtqtk;         ns = 8; K = 256; base = 1024; }
  else if (bid < 1536) { src = tk_w;  dst = wtqtk + 65536; ns = 8; K = 256; base = 1280; }
  else if (bid < 2048) { src = ff1_w; dst = wff1;          ns = 9; K = 256; base = 1536; }
  else                 { src = ff2_w; dst = wff2;          ns = 8; K = 512; base = 2048; }
  const int idx = (bid - base) * 256 + tid;
  const int k = idx >> ns, n = idx & ((1 << ns) - 1);
  dst[n * K + k] = f2bf(src[idx]);
}

// ---------------------------------------------------------------------------
// Prep: flatb = bf16(seq gathered to [M,256]); fpb = bf16(seq + ts).
// ---------------------------------------------------------------------------
__global__ __launch_bounds__(256)
void prep_kernel(const float* __restrict__ seq, const float* __restrict__ ts,
                 unsigned short* __restrict__ flatb, unsigned short* __restrict__ fpb) {
  const int row = blockIdx.x * 8 + (threadIdx.x >> 5);
  const int c0 = (threadIdx.x & 31) * 8;
  const int bn = row >> 8, s = row & 255;
  const int b = bn >> 5, n = bn & 31;
  const float* sp = &seq[((((b << 8) + s) << 5) + n) * 256 + c0];
  const float* tp = &ts[(((b << 8) + s) << 8) + c0];
  const float4 a0 = *(const float4*)sp, a1 = *(const float4*)(sp + 4);
  const float4 t0 = *(const float4*)tp, t1 = *(const float4*)(tp + 4);
  short8 fv, gv;
  fv[0] = (short)f2bf(a0.x); fv[1] = (short)f2bf(a0.y);
  fv[2] = (short)f2bf(a0.z); fv[3] = (short)f2bf(a0.w);
  fv[4] = (short)f2bf(a1.x); fv[5] = (short)f2bf(a1.y);
  fv[6] = (short)f2bf(a1.z); fv[7] = (short)f2bf(a1.w);
  gv[0] = (short)f2bf(a0.x + t0.x); gv[1] = (short)f2bf(a0.y + t0.y);
  gv[2] = (short)f2bf(a0.z + t0.z); gv[3] = (short)f2bf(a0.w + t0.w);
  gv[4] = (short)f2bf(a1.x + t1.x); gv[5] = (short)f2bf(a1.y + t1.y);
  gv[6] = (short)f2bf(a1.z + t1.z); gv[7] = (short)f2bf(a1.w + t1.w);
  *(short8*)&flatb[row * 256 + c0] = fv;
  *(short8*)&fpb[row * 256 + c0] = gv;
}

// ---------------------------------------------------------------------------
// bf16 MFMA GEMM: C[M,NOUT] = epilogue(A @ W + bias)
// AMODE: 0 = fp32 A[M,K]; 3 = bf16 A[M,K]
// RESMODE: 0 none; 2 + resb (bf16 [M,NOUT])
// DUALB: bias for col<256, bias2 for col>=256. SCALEH: post_scale only col<256.
// ---------------------------------------------------------------------------
template<int AMODE, int RESMODE, bool GELU_, int K, int NOUT, bool OUTBF,
         bool DUALB, bool SCALEH>
__global__ __launch_bounds__(256)
void mmb_kernel(const void* __restrict__ Av, const unsigned short* __restrict__ Wt,
                const float* __restrict__ bias, const float* __restrict__ bias2,
                const unsigned short* __restrict__ resb,
                void* __restrict__ Cv, float post_scale) {
  __shared__ unsigned short As[128][72];
  __shared__ unsigned short Bs[128][72];
  const int tid = threadIdx.x;
  const int m0 = blockIdx.x * 128, n0 = blockIdx.y * 128;
  const int l = tid & 63, w = tid >> 6;
  const int wr = w >> 1, wc = w & 1;
  const int lr = l & 15, lg = l >> 4;
  f32x4 acc[4][4] = {};

  for (int k0 = 0; k0 < K; k0 += 64) {
    if (AMODE == 3) {
      const unsigned short* Ab = (const unsigned short*)Av;
#pragma unroll
      for (int i = 0; i < 4; ++i) {
        const int seg = i * 256 + tid;
        const int r = seg >> 3, c8 = (seg & 7) * 8;
        const short8 v = *(const short8*)&Ab[(m0 + r) * K + k0 + c8];
        *(short8*)&As[r][c8] = v;
      }
    } else {
#pragma unroll
      for (int i = 0; i < 8; ++i) {
        const int seg = i * 256 + tid;
        const int r = seg >> 4, c4 = (seg & 15) * 4;
        const float4 a4 = *(const float4*)&((const float*)Av)[(m0 + r) * K + k0 + c4];
        short4v sv;
        sv[0] = (short)f2bf(a4.x); sv[1] = (short)f2bf(a4.y);
        sv[2] = (short)f2bf(a4.z); sv[3] = (short)f2bf(a4.w);
        *(short4v*)&As[r][c4] = sv;
      }
    }
#pragma unroll
    for (int i = 0; i < 4; ++i) {
      const int seg = i * 256 + tid;
      const int n = seg >> 3, c8 = (seg & 7) * 8;
      const short8 v = *(const short8*)&Wt[(n0 + n) * K + k0 + c8];
      *(short8*)&Bs[n][c8] = v;
    }
    __syncthreads();
#pragma unroll
    for (int ks = 0; ks < 2; ++ks) {
      short8 af[4], bfr[4];
#pragma unroll
      for (int qt = 0; qt < 4; ++qt)
        af[qt] = *(const short8*)&As[wr * 64 + qt * 16 + lr][ks * 32 + lg * 8];
#pragma unroll
      for (int nt = 0; nt < 4; ++nt)
        bfr[nt] = *(const short8*)&Bs[wc * 64 + nt * 16 + lr][ks * 32 + lg * 8];
#pragma unroll
      for (int qt = 0; qt < 4; ++qt)
#pragma unroll
        for (int nt = 0; nt < 4; ++nt)
          acc[qt][nt] = __builtin_amdgcn_mfma_f32_16x16x32_bf16(
              af[qt], bfr[nt], acc[qt][nt], 0, 0, 0);
    }
    __syncthreads();
  }

#pragma unroll
  for (int qt = 0; qt < 4; ++qt) {
#pragma unroll
    for (int nt = 0; nt < 4; ++nt) {
      const int col = n0 + wc * 64 + nt * 16 + lr;
      const float bsv = DUALB ? (col < 256 ? bias[col] : bias2[col - 256])
                              : bias[col];
      const float sc = SCALEH ? (col < 256 ? post_scale : 1.0f) : post_scale;
#pragma unroll
      for (int i = 0; i < 4; ++i) {
        const int row = m0 + wr * 64 + qt * 16 + (lg << 2) + i;
        float v = (acc[qt][nt][i] + bsv) * sc;
        if (RESMODE == 2) v += bf2f(resb[row * NOUT + col]);
        if (GELU_) v = 0.5f * v * (1.0f + erff(v * 0.70710678118654752f));
        if (OUTBF) ((unsigned short*)Cv)[row * NOUT + col] = f2bf(v);
        else       ((float*)Cv)[row * NOUT + col] = v;
      }
    }
  }
}

// ---------------------------------------------------------------------------
// Attention v5: swapped-operand 32x32 MFMA flash, 8 waves x 32 query rows.
// No-max softmax (shift-invariant; scale folded into q/tq at GEMM time):
//   p = masked ? 0 : exp2(sacc).
// P exchange via __shfl_xor(.,32) (pairs lane l <-> l+32); mapping robust to
// the HW k-group convention since V-fragments use the identical convention.
// Direct global O stores (no bounce). LDS 48KB -> 3 blocks/CU.
// ---------------------------------------------------------------------------
__global__ __launch_bounds__(512, 4)
void attn4_kernel(const unsigned short* __restrict__ qkb,   // [M][512] q|k
                  const unsigned short* __restrict__ vb,    // [M][256]
                  const unsigned short* __restrict__ tqtkb, // [BS][512] tq|tk
                  const int* __restrict__ valid,
                  unsigned short* __restrict__ ao) {
  __shared__ __align__(16) char KsB[256 * 128];   // K' [key][d64], swizzled
  __shared__ __align__(16) char VsB[32 * 512];    // V^T [dv][key], swizzled

  const int bh = blockIdx.x;
  const int bn = bh >> 3, h = bh & 7;
  const int b = bn >> 5, n = bn & 31;
  const int tid = threadIdx.x, l = tid & 63, w = tid >> 6;  // w = query chunk
  const int lq = l & 31, hi = l >> 5;
  const int qa = w * 32 + lq;          // this lane's query row

  const unsigned long long bm0 = __ballot(valid[((b << 8) + 0   + l) * 32 + n] != 0);
  const unsigned long long bm1 = __ballot(valid[((b << 8) + 64  + l) * 32 + n] != 0);
  const unsigned long long bm2 = __ballot(valid[((b << 8) + 128 + l) * 32 + n] != 0);
  const unsigned long long bm3 = __ballot(valid[((b << 8) + 192 + l) * 32 + n] != 0);

  // Q' fragments (B-operand): col = own q, k = 8*hi + j per 16-wide K chunk.
  // q columns pre-scaled by c2, tq by 0.25*c2 (folded at GEMM).
  short8 qf[4];
  {
    const unsigned short* qp = &qkb[((bn << 8) + qa) * 512 + (h << 5)];
    const unsigned short* tp = &tqtkb[((b << 8) + qa) * 512 + (h << 5)];
    qf[0] = *(const short8*)&qp[hi * 8];
    qf[1] = *(const short8*)&qp[16 + hi * 8];
    qf[2] = *(const short8*)&tp[hi * 8];
    qf[3] = *(const short8*)&tp[16 + hi * 8];
  }

  // stage K' (k | tk), swizzled: byte = key*128 + ((c*16) ^ ((key&7)<<4))
#pragma unroll
  for (int i = 0; i < 4; ++i) {
    const int e = i * 512 + tid;
    const int key = e >> 3, c = e & 7;
    const unsigned short* src = (c < 4)
        ? &qkb[((bn << 8) + key) * 512 + 256 + (h << 5) + c * 8]
        : &tqtkb[((b << 8) + key) * 512 + 256 + (h << 5) + (c - 4) * 8];
    *(short8*)(KsB + key * 128 + ((c * 16) ^ ((key & 7) << 4))) = *(const short8*)src;
  }
  // stage V^T, swizzled: byte = dv*512 + ((key*2) ^ ((dv&7)<<4))
#pragma unroll
  for (int i = 0; i < 2; ++i) {
    const int e = i * 512 + tid;
    const int key = e >> 2, c = e & 3;
    const short8 v = *(const short8*)&vb[((bn << 8) + key) * 256 + (h << 5) + c * 8];
#pragma unroll
    for (int j = 0; j < 8; ++j) {
      const int dv = c * 8 + j;
      *(unsigned short*)(VsB + dv * 512 + ((key * 2) ^ ((dv & 7) << 4))) =
          (unsigned short)v[j];
    }
  }
  __syncthreads();

  f32x16 oacc = {};
  float lrun = 0.0f;

  for (int g = 0; g <= w; ++g) {
    const int kbase = g << 5;
    // S^T = mfma(K'_tile, Q') -- already in log2 domain (scale folded)
    f32x16 s = {};
#pragma unroll
    for (int df = 0; df < 4; ++df) {
      const int key = kbase + lq;
      const short8 akf = *(const short8*)(
          KsB + key * 128 + ((df * 32 + hi * 16) ^ ((key & 7) << 4)));
      s = __builtin_amdgcn_mfma_f32_32x32x16_bf16(akf, qf[df], s, 0, 0, 0);
    }
    const unsigned long long bmc = (kbase < 64) ? bm0 : (kbase < 128) ? bm1
                                 : (kbase < 192) ? bm2 : bm3;
    const unsigned wnd = (kbase & 32) ? (unsigned)(bmc >> 32) : (unsigned)bmc;
    // p = masked ? 0 : exp2(s)   (no-max online softmax)
    float p[16];
#pragma unroll
    for (int r = 0; r < 16; ++r) {
      const int crow = (r & 3) + 8 * (r >> 2) + 4 * hi;
      const int key = kbase + crow;
      const bool ok = (key <= qa) && (((wnd >> crow) & 1u) != 0u);
      p[r] = ok ? __builtin_amdgcn_exp2f(s[r]) : 0.0f;
    }
    float rs = ((p[0] + p[1]) + (p[2] + p[3])) + ((p[4] + p[5]) + (p[6] + p[7]))
             + ((p[8] + p[9]) + (p[10] + p[11])) + ((p[12] + p[13]) + (p[14] + p[15]));
    rs += __shfl_xor(rs, 32);
    lrun += rs;
    // pack to bf16 pairs and exchange halves via shfl_xor(32)
    unsigned wds[8];
#pragma unroll
    for (int i2 = 0; i2 < 8; ++i2)
      wds[i2] = (unsigned)f2bf(p[2 * i2]) | ((unsigned)f2bf(p[2 * i2 + 1]) << 16);
    unsigned xw[8];
#pragma unroll
    for (int i2 = 0; i2 < 8; ++i2)
      xw[i2] = (unsigned)__shfl_xor((int)wds[i2], 32);
    // B-fragments: frag0 = keys kbase+hi*8+j, frag1 = keys kbase+16+hi*8+j
    i32x4 f0, f1;
    f0[0] = (int)(hi ? xw[2] : wds[0]);
    f0[1] = (int)(hi ? xw[3] : wds[1]);
    f0[2] = (int)(hi ? wds[2] : xw[0]);
    f0[3] = (int)(hi ? wds[3] : xw[1]);
    f1[0] = (int)(hi ? xw[6] : wds[4]);
    f1[1] = (int)(hi ? xw[7] : wds[5]);
    f1[2] = (int)(hi ? wds[6] : xw[4]);
    f1[3] = (int)(hi ? wds[7] : xw[5]);
    const short8 pf0 = __builtin_bit_cast(short8, f0);
    const short8 pf1 = __builtin_bit_cast(short8, f1);
    // PV: O^T += mfma(V^T, P)
    {
      const short8 avf = *(const short8*)(
          VsB + lq * 512 + (((kbase + hi * 8) * 2) ^ ((lq & 7) << 4)));
      oacc = __builtin_amdgcn_mfma_f32_32x32x16_bf16(avf, pf0, oacc, 0, 0, 0);
    }
    {
      const short8 avf = *(const short8*)(
          VsB + lq * 512 + (((kbase + 16 + hi * 8) * 2) ^ ((lq & 7) << 4)));
      oacc = __builtin_amdgcn_mfma_f32_32x32x16_bf16(avf, pf1, oacc, 0, 0, 0);
    }
  }

  // degenerate rows: no valid causal key -> uniform over ALL valid keys
  if (lrun == 0.0f) {
    float cnt = 0.0f;
    f32x16 os = {};
    for (int key = 0; key < 256; ++key) {
      const unsigned long long bmc = (key < 64) ? bm0 : (key < 128) ? bm1
                                   : (key < 192) ? bm2 : bm3;
      if ((bmc >> (key & 63)) & 1ull) {
        cnt += 1.0f;
#pragma unroll
        for (int r = 0; r < 16; ++r) {
          const int dv = (r & 3) + 8 * (r >> 2) + 4 * hi;
          os[r] += bf2f(*(const unsigned short*)(
              VsB + dv * 512 + ((key * 2) ^ ((dv & 7) << 4))));
        }
      }
    }
    oacc = os; lrun = cnt;
  }

  // direct store: lane holds O^T[dv=crow(r,hi)][q=lq]; groups of 4 dv -> 8B
  const float inv = 1.0f / fmaxf(lrun, 1e-6f);
  const int row = (bn << 8) + qa;
#pragma unroll
  for (int g2 = 0; g2 < 4; ++g2) {
    const unsigned long long h0 = f2bf(oacc[4 * g2 + 0] * inv);
    const unsigned long long h1 = f2bf(oacc[4 * g2 + 1] * inv);
    const unsigned long long h2 = f2bf(oacc[4 * g2 + 2] * inv);
    const unsigned long long h3 = f2bf(oacc[4 * g2 + 3] * inv);
    const unsigned long long pkt = h0 | (h1 << 16) | (h2 << 32) | (h3 << 48);
    *(unsigned long long*)&ao[row * 256 + (h << 5) + 8 * g2 + 4 * hi] = pkt;
  }
}

// ---------------------------------------------------------------------------
// LN1: fp32 in -> bf16 out (flat). LN2: fp32 in -> fp32 out, *valid, scatter.
// ---------------------------------------------------------------------------
__global__ __launch_bounds__(256)
void ln1_kernel(const float* __restrict__ X, const float* __restrict__ g,
                const float* __restrict__ bb, unsigned short* __restrict__ out) {
  const int row = blockIdx.x * 4 + (threadIdx.x >> 6);
  const int lane = threadIdx.x & 63;
  const float4 x = *(const float4*)&X[row * 256 + lane * 4];
  float s1 = x.x + x.y + x.z + x.w;
#pragma unroll
  for (int off = 1; off < 64; off <<= 1) s1 += __shfl_xor(s1, off);
  const float mean = s1 * (1.0f / 256.0f);
  const float dx = x.x - mean, dy = x.y - mean, dz = x.z - mean, dw = x.w - mean;
  float s2 = dx * dx + dy * dy + dz * dz + dw * dw;
#pragma unroll
  for (int off = 1; off < 64; off <<= 1) s2 += __shfl_xor(s2, off);
  const float rstd = rsqrtf(s2 * (1.0f / 256.0f) + 1e-5f);
  const int c0 = lane * 4;
  short4v y;
  y[0] = (short)f2bf(dx * rstd * g[c0] + bb[c0]);
  y[1] = (short)f2bf(dy * rstd * g[c0 + 1] + bb[c0 + 1]);
  y[2] = (short)f2bf(dz * rstd * g[c0 + 2] + bb[c0 + 2]);
  y[3] = (short)f2bf(dw * rstd * g[c0 + 3] + bb[c0 + 3]);
  *(short4v*)&out[row * 256 + c0] = y;
}

__global__ __launch_bounds__(256)
void ln2_kernel(const float* __restrict__ X, const float* __restrict__ g,
                const float* __restrict__ bb, float* __restrict__ out,
                const int* __restrict__ valid) {
  const int row = blockIdx.x * 4 + (threadIdx.x >> 6);
  const int lane = threadIdx.x & 63;
  const float4 x = *(const float4*)&X[row * 256 + lane * 4];
  float s1 = x.x + x.y + x.z + x.w;
#pragma unroll
  for (int off = 1; off < 64; off <<= 1) s1 += __shfl_xor(s1, off);
  const float mean = s1 * (1.0f / 256.0f);
  const float dx = x.x - mean, dy = x.y - mean, dz = x.z - mean, dw = x.w - mean;
  float s2 = dx * dx + dy * dy + dz * dz + dw * dw;
#pragma unroll
  for (int off = 1; off < 64; off <<= 1) s2 += __shfl_xor(s2, off);
  const float rstd = rsqrtf(s2 * (1.0f / 256.0f) + 1e-5f);
  const int c0 = lane * 4;
  const int bn = row >> 8, s = row & 255;
  const int b = bn >> 5, n = bn & 31;
  const float vmv = (valid[((b << 8) + s) * 32 + n] != 0) ? 1.0f : 0.0f;
  float4 y;
  y.x = (dx * rstd * g[c0] + bb[c0]) * vmv;
  y.y = (dy * rstd * g[c0 + 1] + bb[c0 + 1]) * vmv;
  y.z = (dz * rstd * g[c0 + 2] + bb[c0 + 2]) * vmv;
  y.w = (dw * rstd * g[c0 + 3] + bb[c0 + 3]) * vmv;
  *(float4*)&out[(((((b << 8) + s) << 5) + n) << 8) + c0] = y;
}

// ---------------------------------------------------------------------------
extern "C" void kernel_launch(void* const* d_in, const int* in_sizes, int n_in,
                              void* d_out, int out_size, void* d_ws, size_t ws_size,
                              hipStream_t stream) {
  const float* seq    = (const float*)d_in[0];
  const float* regs   = (const float*)d_in[1];
  const float* trs    = (const float*)d_in[2];
  const float* q_w    = (const float*)d_in[3];
  const float* q_b    = (const float*)d_in[4];
  const float* k_w    = (const float*)d_in[5];
  const float* k_b    = (const float*)d_in[6];
  const float* v_w    = (const float*)d_in[7];
  const float* v_b    = (const float*)d_in[8];
  const float* o_w    = (const float*)d_in[9];
  const float* o_b    = (const float*)d_in[10];
  const float* semb   = (const float*)d_in[11];
  const float* reg_w  = (const float*)d_in[12];
  const float* reg_b  = (const float*)d_in[13];
  const float* tr_w   = (const float*)d_in[14];
  const float* tr_b   = (const float*)d_in[15];
  const float* tq_w   = (const float*)d_in[16];
  const float* tq_b   = (const float*)d_in[17];
  const float* tk_w   = (const float*)d_in[18];
  const float* tk_b   = (const float*)d_in[19];
  const float* ff_w1  = (const float*)d_in[20];
  const float* ff_b1  = (const float*)d_in[21];
  const float* ff_w2  = (const float*)d_in[22];
  const float* ff_b2  = (const float*)d_in[23];
  const float* ln1_g  = (const float*)d_in[24];
  const float* ln1_b  = (const float*)d_in[25];
  const float* ln2_g  = (const float*)d_in[26];
  const float* ln2_b  = (const float*)d_in[27];
  const int*   valid  = (const int*)d_in[28];
  const int*   codes  = (const int*)d_in[29];

  float* f32ws = (float*)d_ws;
  float* ts    = f32ws;                 // 262144 f
  float* x1pre = f32ws + 262144;        // 8388608 f (reused as x2)
  unsigned short* bws = (unsigned short*)(f32ws + 262144 + 8388608);
  unsigned short* flatb = bws;                    // 8388608  (x1b alias)
  unsigned short* fpb   = bws + 8388608;          // 8388608  (ao alias)
  unsigned short* qkb   = bws + 16777216;         // 16777216 (h1 alias)
  unsigned short* vb    = bws + 33554432;         // 8388608
  unsigned short* tqtkb = bws + 41943040;         // 524288
  unsigned short* wqk   = bws + 42467328;         // 131072
  unsigned short* wv    = bws + 42598400;         // 65536
  unsigned short* wo    = bws + 42663936;         // 65536
  unsigned short* wtqtk = bws + 42729472;         // 131072
  unsigned short* wff1  = bws + 42860544;         // 131072
  unsigned short* wff2  = bws + 42991616;         // 131072  (end 43122688)
  unsigned short* ao  = fpb;
  unsigned short* x1b = flatb;
  unsigned short* h1  = qkb;
  float* x2 = x1pre;
  float* outp = (float*)d_out;

  const float c2 = 0.25505402f;  // (1/sqrt(32)) * log2(e) -- folded into q/tq

  // 1. time state + weight conversion (independent)
  ts_kernel<<<BS_, 256, 0, stream>>>(regs, trs, codes, semb, reg_w, reg_b,
                                     tr_w, tr_b, ts);
  cvtall_kernel<<<2560, 256, 0, stream>>>(q_w, k_w, v_w, o_w, tq_w, tk_w,
                                          ff_w1, ff_w2, wqk, wv, wo, wtqtk,
                                          wff1, wff2);
  // 2. prep: flatb = bf16(flat), fpb = bf16(flat + ts)
  prep_kernel<<<M_ / 8, 256, 0, stream>>>(seq, ts, flatb, fpb);
  // 3. temporal projections merged (tq|tk); 0.25*c2 folded into tq half
  mmb_kernel<0, 0, false, 256, 512, true, true, true>
      <<<dim3(8, 4), 256, 0, stream>>>(ts, wtqtk, tq_b, tk_b, nullptr,
                                       tqtkb, 0.25f * c2);
  // 4. q|k merged projection (c2 folded into q half); v projection
  mmb_kernel<3, 0, false, 256, 512, true, true, true>
      <<<dim3(256, 4), 256, 0, stream>>>(fpb, wqk, q_b, k_b, nullptr,
                                         qkb, c2);
  mmb_kernel<3, 0, false, 256, 256, true, false, false>
      <<<dim3(256, 2), 256, 0, stream>>>(flatb, wv, v_b, nullptr, nullptr,
                                         vb, 1.0f);
  // 5. attention (v5: no-max softmax, shfl exchange, direct stores)
  attn4_kernel<<<BN_ * NH_, 512, 0, stream>>>(qkb, vb, tqtkb, valid, ao);
  // 6. o-proj + flat residual (bf16) -> x1pre (fp32); LN1 -> x1b (bf16)
  mmb_kernel<3, 2, false, 256, 256, false, false, false>
      <<<dim3(256, 2), 256, 0, stream>>>(ao, wo, o_b, nullptr, flatb,
                                         x1pre, 1.0f);
  ln1_kernel<<<M_ / 4, 256, 0, stream>>>(x1pre, ln1_g, ln1_b, x1b);
  // 7. FF
  mmb_kernel<3, 0, true, 256, 512, true, false, false>
      <<<dim3(256, 4), 256, 0, stream>>>(x1b, wff1, ff_b1, nullptr, nullptr,
                                         h1, 1.0f);
  mmb_kernel<3, 2, false, 512, 256, false, false, false>
      <<<dim3(256, 2), 256, 0, stream>>>(h1, wff2, ff_b2, nullptr, x1b,
                                         x2, 1.0f);
  // 8. LN2 * valid -> output layout
  ln2_kernel<<<M_ / 4, 256, 0, stream>>>(x2, ln2_g, ln2_b, outp, valid);
}